// Round 1
// baseline (1421.608 us; speedup 1.0000x reference)
//
#include <hip/hip_runtime.h>

#define NN 50000
#define NE 800000
#define NG 512
#define HC 64
#define NL 5
#define GD_COLS 321
#define BN_EPS 1e-5f

// ---------------- layer 0 (C_IN = 1) ----------------

__global__ void copy0_kernel(const float* __restrict__ x, float* __restrict__ z0) {
    int i = blockIdx.x * blockDim.x + threadIdx.x;
    if (i < NN) z0[i] = x[i];
}

__global__ void edge_agg0_kernel(const int* __restrict__ ei, const float* __restrict__ x,
                                 float* __restrict__ z0) {
    int e = blockIdx.x * blockDim.x + threadIdx.x;
    if (e < NE) {
        int s = ei[e];
        int d = ei[NE + e];
        atomicAdd(&z0[d], x[s]);
    }
}

// y[r][c] = z0[r]*w1_0[c] + b1[c]; accumulate per-channel sum/sumsq
__global__ void rank1_stats_kernel(const float* __restrict__ z0, const float* __restrict__ w,
                                   const float* __restrict__ bias, float* __restrict__ y,
                                   float* __restrict__ stats) {
    int lane = threadIdx.x & 63;
    int wid = threadIdx.x >> 6;
    int r0 = blockIdx.x * 256 + wid * 64;
    float wv = w[lane];
    float bv = bias[lane];
    float s = 0.f, s2 = 0.f;
    for (int j = 0; j < 64; ++j) {
        int r = r0 + j;
        if (r < NN) {
            float v = z0[r] * wv + bv;
            y[r * HC + lane] = v;
            s += v;
            s2 += v * v;
        }
    }
    __shared__ float ls[256], ls2[256];
    ls[threadIdx.x] = s;
    ls2[threadIdx.x] = s2;
    __syncthreads();
    if (wid == 0) {
        float ts = ls[lane] + ls[64 + lane] + ls[128 + lane] + ls[192 + lane];
        float t2 = ls2[lane] + ls2[64 + lane] + ls2[128 + lane] + ls2[192 + lane];
        atomicAdd(&stats[lane], ts);
        atomicAdd(&stats[64 + lane], t2);
    }
}

// ---------------- generic pieces ----------------

__global__ void copy_vec_kernel(const float* __restrict__ src, float* __restrict__ dst, int n4) {
    int i = blockIdx.x * blockDim.x + threadIdx.x;
    if (i < n4) ((float4*)dst)[i] = ((const float4*)src)[i];
}

// wave per edge, lane per channel: z[dst][lane] += h[src][lane]
__global__ void edge_agg_kernel(const int* __restrict__ ei, const float* __restrict__ h,
                                float* __restrict__ z) {
    int e = (blockIdx.x * blockDim.x + threadIdx.x) >> 6;
    int lane = threadIdx.x & 63;
    if (e < NE) {
        int s = ei[e];
        int d = ei[NE + e];
        float v = h[s * HC + lane];
        atomicAdd(&z[d * HC + lane], v);
    }
}

// out = (NORM ? relu(bn(in)) : in) @ w + bias; accumulate per-channel stats of out.
// 64 rows per block, 256 threads. w staged in LDS, input rows staged in LDS.
template <bool NORM>
__global__ void gemm64_kernel(const float* __restrict__ in, const float* __restrict__ w,
                              const float* __restrict__ bias, const float* __restrict__ statsIn,
                              const float* __restrict__ gIn, const float* __restrict__ bIn,
                              float* __restrict__ out, float* __restrict__ statsOut) {
    __shared__ float zs[64 * 64];
    __shared__ float wsm[64 * 64];
    __shared__ float a1[64], s1[64];
    int t = threadIdx.x;
    if (NORM) {
        if (t < 64) {
            float mu = statsIn[t] * (1.0f / NN);
            float var = statsIn[64 + t] * (1.0f / NN) - mu * mu;
            float a = gIn[t] * rsqrtf(var + BN_EPS);
            a1[t] = a;
            s1[t] = bIn[t] - mu * a;
        }
        __syncthreads();
    }
    int r0 = blockIdx.x * 64;
    // cooperative staging: 4096 floats = 1024 float4
    for (int idx = t; idx < 1024; idx += 256) {
        int off = idx * 4;
        int r = r0 + (off >> 6);
        int k = off & 63;
        float4 v;
        if (r < NN)
            v = *(const float4*)&in[r * HC + k];
        else
            v = make_float4(0.f, 0.f, 0.f, 0.f);
        if (NORM) {
            v.x = fmaxf(v.x * a1[k] + s1[k], 0.f);
            v.y = fmaxf(v.y * a1[k + 1] + s1[k + 1], 0.f);
            v.z = fmaxf(v.z * a1[k + 2] + s1[k + 2], 0.f);
            v.w = fmaxf(v.w * a1[k + 3] + s1[k + 3], 0.f);
        }
        *(float4*)&zs[off] = v;
    }
    for (int idx = t; idx < 1024; idx += 256) {
        int off = idx * 4;
        *(float4*)&wsm[off] = *(const float4*)&w[off];
    }
    __syncthreads();
    int lane = t & 63, wid = t >> 6;
    float bv = bias[lane];
    float ssum = 0.f, ssq = 0.f;
    for (int j = 0; j < 16; ++j) {
        int r = wid * 16 + j;  // local row
        float acc = 0.f;
#pragma unroll
        for (int k = 0; k < 64; k += 4) {
            float4 zv = *(const float4*)&zs[r * 64 + k];
            acc += zv.x * wsm[(k + 0) * 64 + lane];
            acc += zv.y * wsm[(k + 1) * 64 + lane];
            acc += zv.z * wsm[(k + 2) * 64 + lane];
            acc += zv.w * wsm[(k + 3) * 64 + lane];
        }
        acc += bv;
        int gr = r0 + r;
        if (gr < NN) {
            out[gr * HC + lane] = acc;
            ssum += acc;
            ssq += acc * acc;
        }
    }
    __shared__ float red[512];
    red[t] = ssum;
    red[256 + t] = ssq;
    __syncthreads();
    if (wid == 0) {
        float ts = red[lane] + red[64 + lane] + red[128 + lane] + red[192 + lane];
        float t2 = red[256 + lane] + red[256 + 64 + lane] + red[256 + 128 + lane] +
                   red[256 + 192 + lane];
        atomicAdd(&statsOut[lane], ts);
        atomicAdd(&statsOut[64 + lane], t2);
    }
}

// BN2 + ReLU, write new h, and segmented (sorted batch) graph sum into gdesc.
// One 64-thread block per CH-node chunk; lane = channel.
#define CHK 128
__global__ void bn_relu_seg_kernel(const float* __restrict__ u, const float* __restrict__ stats,
                                   const float* __restrict__ g, const float* __restrict__ b,
                                   const int* __restrict__ batch, float* __restrict__ h,
                                   float* __restrict__ gdesc, int layer) {
    int lane = threadIdx.x;
    int i0 = blockIdx.x * CHK;
    float mu = stats[lane] * (1.0f / NN);
    float var = stats[64 + lane] * (1.0f / NN) - mu * mu;
    float a = g[lane] * rsqrtf(var + BN_EPS);
    float s = b[lane] - mu * a;
    int col = 1 + layer * HC + lane;
    float acc = 0.f;
    int cur = -1;
    int iend = i0 + CHK;
    if (iend > NN) iend = NN;
    for (int i = i0; i < iend; ++i) {
        int gid = batch[i];
        if (gid != cur) {
            if (cur >= 0) atomicAdd(&gdesc[cur * GD_COLS + col], acc);
            cur = gid;
            acc = 0.f;
        }
        float v = fmaxf(u[i * HC + lane] * a + s, 0.f);
        h[i * HC + lane] = v;
        acc += v;
    }
    if (cur >= 0) atomicAdd(&gdesc[cur * GD_COLS + col], acc);
}

__global__ void first_desc_kernel(const float* __restrict__ x, const int* __restrict__ batch,
                                  float* __restrict__ gdesc) {
    int i = blockIdx.x * blockDim.x + threadIdx.x;
    if (i < NN) atomicAdd(&gdesc[batch[i] * GD_COLS], x[i]);
}

__global__ void final_gemm_kernel(const float* __restrict__ gdesc, const float* __restrict__ lw,
                                  const float* __restrict__ lb, float* __restrict__ out) {
    int g = blockIdx.x;
    int lane = threadIdx.x;  // 64
    float a0 = 0.f, a1 = 0.f;
    for (int j = lane; j < GD_COLS; j += 64) {
        float v = gdesc[g * GD_COLS + j];
        a0 += v * lw[j * 2 + 0];
        a1 += v * lw[j * 2 + 1];
    }
    for (int off = 32; off > 0; off >>= 1) {
        a0 += __shfl_down(a0, off);
        a1 += __shfl_down(a1, off);
    }
    if (lane == 0) {
        out[g * 2 + 0] = a0 + lb[0];
        out[g * 2 + 1] = a1 + lb[1];
    }
}

extern "C" void kernel_launch(void* const* d_in, const int* in_sizes, int n_in, void* d_out,
                              int out_size, void* d_ws, size_t ws_size, hipStream_t stream) {
    const float* x = (const float*)d_in[0];
    const int* ei = (const int*)d_in[1];
    const int* batch = (const int*)d_in[2];
    const float* w1_0 = (const float*)d_in[3];
    const float* w1_rest = (const float*)d_in[4];
    const float* b1 = (const float*)d_in[5];
    const float* gm = (const float*)d_in[6];
    const float* bm = (const float*)d_in[7];
    const float* w2 = (const float*)d_in[8];
    const float* b2 = (const float*)d_in[9];
    const float* go = (const float*)d_in[10];
    const float* bo = (const float*)d_in[11];
    const float* lw = (const float*)d_in[12];
    const float* lb = (const float*)d_in[13];
    float* out = (float*)d_out;

    float* bufA = (float*)d_ws;          // h / y   (N*64)
    float* bufB = bufA + (size_t)NN * HC;  // z / u   (N*64)
    float* z0 = bufB + (size_t)NN * HC;    // N
    float* stats = z0 + NN;              // NL*256
    float* gdesc = stats + NL * 256;     // NG*321

    hipMemsetAsync(stats, 0, (NL * 256 + NG * GD_COLS) * sizeof(float), stream);

    // ---- layer 0 ----
    copy0_kernel<<<(NN + 255) / 256, 256, 0, stream>>>(x, z0);
    edge_agg0_kernel<<<(NE + 255) / 256, 256, 0, stream>>>(ei, x, z0);
    rank1_stats_kernel<<<(NN + 255) / 256, 256, 0, stream>>>(z0, w1_0, b1, bufA, stats);
    gemm64_kernel<true><<<(NN + 63) / 64, 256, 0, stream>>>(bufA, w2, b2, stats, gm, bm, bufB,
                                                            stats + 128);
    bn_relu_seg_kernel<<<(NN + CHK - 1) / CHK, 64, 0, stream>>>(bufB, stats + 128, go, bo, batch,
                                                                bufA, gdesc, 0);

    // ---- layers 1..4 ----
    for (int l = 1; l < NL; ++l) {
        float* st1 = stats + l * 256;
        float* st2 = st1 + 128;
        copy_vec_kernel<<<(NN * HC / 4 + 255) / 256, 256, 0, stream>>>(bufA, bufB, NN * HC / 4);
        edge_agg_kernel<<<(NE * 64) / 256, 256, 0, stream>>>(ei, bufA, bufB);
        gemm64_kernel<false><<<(NN + 63) / 64, 256, 0, stream>>>(
            bufB, w1_rest + (size_t)(l - 1) * HC * HC, b1 + l * HC, nullptr, nullptr, nullptr,
            bufA, st1);
        gemm64_kernel<true><<<(NN + 63) / 64, 256, 0, stream>>>(
            bufA, w2 + (size_t)l * HC * HC, b2 + l * HC, st1, gm + l * HC, bm + l * HC, bufB, st2);
        bn_relu_seg_kernel<<<(NN + CHK - 1) / CHK, 64, 0, stream>>>(
            bufB, st2, go + l * HC, bo + l * HC, batch, bufA, gdesc, l);
    }

    first_desc_kernel<<<(NN + 255) / 256, 256, 0, stream>>>(x, batch, gdesc);
    final_gemm_kernel<<<NG, 64, 0, stream>>>(gdesc, lw, lb, out);
}

// Round 2
// 1147.656 us; speedup vs baseline: 1.2387x; 1.2387x over previous
//
#include <hip/hip_runtime.h>

#define NN 50000
#define NE 800000
#define NG 512
#define HC 64
#define NL 5
#define GD_COLS 321
#define BN_EPS 1e-5f
#define NT 196  // scan tiles of 256 covering NN

// ---------------- CSR build (edges sorted by dst), done once per call ----------------

__global__ void hist_kernel(const int* __restrict__ ei, int* __restrict__ counts) {
    int e = blockIdx.x * blockDim.x + threadIdx.x;
    if (e < NE) atomicAdd(&counts[ei[NE + e]], 1);
}

// per-tile exclusive scan; tile totals out
__global__ void scan_a_kernel(const int* __restrict__ counts, int* __restrict__ row_start,
                              int* __restrict__ tile_sums) {
    __shared__ int sh[256];
    int t = threadIdx.x;
    int i = blockIdx.x * 256 + t;
    int c = (i < NN) ? counts[i] : 0;
    sh[t] = c;
    __syncthreads();
    for (int ofs = 1; ofs < 256; ofs <<= 1) {
        int v = (t >= ofs) ? sh[t - ofs] : 0;
        __syncthreads();
        sh[t] += v;
        __syncthreads();
    }
    if (i < NN) row_start[i] = sh[t] - c;  // exclusive within tile
    if (t == 255) tile_sums[blockIdx.x] = sh[255];
}

__global__ void scan_b_kernel(int* __restrict__ tile_sums) {
    __shared__ int sh[256];
    int t = threadIdx.x;
    int v = (t < NT) ? tile_sums[t] : 0;
    sh[t] = v;
    __syncthreads();
    for (int ofs = 1; ofs < 256; ofs <<= 1) {
        int u = (t >= ofs) ? sh[t - ofs] : 0;
        __syncthreads();
        sh[t] += u;
        __syncthreads();
    }
    if (t < NT) tile_sums[t] = sh[t] - v;  // exclusive tile offsets, in place
}

__global__ void scan_c_kernel(int* __restrict__ row_start, const int* __restrict__ tile_sums,
                              int* __restrict__ cursor) {
    int i = blockIdx.x * 256 + threadIdx.x;
    if (i < NN) {
        int v = row_start[i] + tile_sums[blockIdx.x];
        row_start[i] = v;
        cursor[i] = v;
    }
    if (i == 0) row_start[NN] = NE;
}

__global__ void scatter_kernel(const int* __restrict__ ei, int* __restrict__ cursor,
                               int* __restrict__ ssrc) {
    int e = blockIdx.x * blockDim.x + threadIdx.x;
    if (e < NE) {
        int d = ei[NE + e];
        int pos = atomicAdd(&cursor[d], 1);
        ssrc[pos] = ei[e];
    }
}

// ---------------- layer 0 (C_IN = 1) ----------------

__global__ void gather0_kernel(const float* __restrict__ x, const int* __restrict__ row_start,
                               const int* __restrict__ ssrc, float* __restrict__ z0) {
    int i = blockIdx.x * blockDim.x + threadIdx.x;
    if (i < NN) {
        float acc = x[i];
        int pb = row_start[i + 1];
        for (int p = row_start[i]; p < pb; ++p) acc += x[ssrc[p]];
        z0[i] = acc;
    }
}

// y[r][c] = z0[r]*w1_0[c] + b1[c]; accumulate per-channel sum/sumsq
__global__ void rank1_stats_kernel(const float* __restrict__ z0, const float* __restrict__ w,
                                   const float* __restrict__ bias, float* __restrict__ y,
                                   float* __restrict__ stats) {
    int lane = threadIdx.x & 63;
    int wid = threadIdx.x >> 6;
    int r0 = blockIdx.x * 256 + wid * 64;
    float wv = w[lane];
    float bv = bias[lane];
    float s = 0.f, s2 = 0.f;
    for (int j = 0; j < 64; ++j) {
        int r = r0 + j;
        if (r < NN) {
            float v = z0[r] * wv + bv;
            y[r * HC + lane] = v;
            s += v;
            s2 += v * v;
        }
    }
    __shared__ float ls[256], ls2[256];
    ls[threadIdx.x] = s;
    ls2[threadIdx.x] = s2;
    __syncthreads();
    if (wid == 0) {
        float ts = ls[lane] + ls[64 + lane] + ls[128 + lane] + ls[192 + lane];
        float t2 = ls2[lane] + ls2[64 + lane] + ls2[128 + lane] + ls2[192 + lane];
        atomicAdd(&stats[lane], ts);
        atomicAdd(&stats[64 + lane], t2);
    }
}

// ---------------- fused gather + GEMM1 + stats (layers 1..4) ----------------
// z[i] = h[i] + sum_{src in CSR(i)} h[src];  y = z @ w + b;  stats of y.
__global__ void gather_gemm_kernel(const float* __restrict__ h, const int* __restrict__ row_start,
                                   const int* __restrict__ ssrc, const float* __restrict__ w,
                                   const float* __restrict__ bias, float* __restrict__ out,
                                   float* __restrict__ statsOut) {
    __shared__ float zs[64 * 64];
    __shared__ float wsm[64 * 64];
    int t = threadIdx.x, lane = t & 63, wid = t >> 6;
    int r0 = blockIdx.x * 64;
    for (int idx = t; idx < 1024; idx += 256)
        *(float4*)&wsm[idx * 4] = *(const float4*)&w[idx * 4];
    // register-accumulated gather, wave-serial over 16 nodes
    for (int j = 0; j < 16; ++j) {
        int gr = r0 + wid * 16 + j;
        float acc = 0.f;
        if (gr < NN) {
            acc = h[gr * HC + lane];
            int pa = row_start[gr], pb = row_start[gr + 1];
            for (int p = pa; p < pb; ++p) {
                int s = ssrc[p];  // wave-uniform
                acc += h[s * HC + lane];
            }
        }
        zs[(wid * 16 + j) * 64 + lane] = acc;
    }
    __syncthreads();
    float bv = bias[lane];
    float ssum = 0.f, ssq = 0.f;
    for (int j = 0; j < 16; ++j) {
        int r = wid * 16 + j;
        float acc = 0.f;
#pragma unroll
        for (int k = 0; k < 64; k += 4) {
            float4 zv = *(const float4*)&zs[r * 64 + k];
            acc += zv.x * wsm[(k + 0) * 64 + lane];
            acc += zv.y * wsm[(k + 1) * 64 + lane];
            acc += zv.z * wsm[(k + 2) * 64 + lane];
            acc += zv.w * wsm[(k + 3) * 64 + lane];
        }
        acc += bv;
        int gr = r0 + r;
        if (gr < NN) {
            out[gr * HC + lane] = acc;
            ssum += acc;
            ssq += acc * acc;
        }
    }
    __shared__ float red[512];
    red[t] = ssum;
    red[256 + t] = ssq;
    __syncthreads();
    if (wid == 0) {
        float ts = red[lane] + red[64 + lane] + red[128 + lane] + red[192 + lane];
        float t2 = red[256 + lane] + red[256 + 64 + lane] + red[256 + 128 + lane] +
                   red[256 + 192 + lane];
        atomicAdd(&statsOut[lane], ts);
        atomicAdd(&statsOut[64 + lane], t2);
    }
}

// ---------------- BN1+ReLU fused into GEMM2 + stats ----------------
__global__ void gemm64_norm_kernel(const float* __restrict__ in, const float* __restrict__ w,
                                   const float* __restrict__ bias,
                                   const float* __restrict__ statsIn, const float* __restrict__ gIn,
                                   const float* __restrict__ bIn, float* __restrict__ out,
                                   float* __restrict__ statsOut) {
    __shared__ float zs[64 * 64];
    __shared__ float wsm[64 * 64];
    __shared__ float a1[64], s1[64];
    int t = threadIdx.x;
    if (t < 64) {
        float mu = statsIn[t] * (1.0f / NN);
        float var = statsIn[64 + t] * (1.0f / NN) - mu * mu;
        float a = gIn[t] * rsqrtf(var + BN_EPS);
        a1[t] = a;
        s1[t] = bIn[t] - mu * a;
    }
    __syncthreads();
    int r0 = blockIdx.x * 64;
    for (int idx = t; idx < 1024; idx += 256) {
        int off = idx * 4;
        int r = r0 + (off >> 6);
        int k = off & 63;
        float4 v;
        if (r < NN)
            v = *(const float4*)&in[r * HC + k];
        else
            v = make_float4(0.f, 0.f, 0.f, 0.f);
        v.x = fmaxf(v.x * a1[k] + s1[k], 0.f);
        v.y = fmaxf(v.y * a1[k + 1] + s1[k + 1], 0.f);
        v.z = fmaxf(v.z * a1[k + 2] + s1[k + 2], 0.f);
        v.w = fmaxf(v.w * a1[k + 3] + s1[k + 3], 0.f);
        *(float4*)&zs[off] = v;
    }
    for (int idx = t; idx < 1024; idx += 256) {
        int off = idx * 4;
        *(float4*)&wsm[off] = *(const float4*)&w[off];
    }
    __syncthreads();
    int lane = t & 63, wid = t >> 6;
    float bv = bias[lane];
    float ssum = 0.f, ssq = 0.f;
    for (int j = 0; j < 16; ++j) {
        int r = wid * 16 + j;
        float acc = 0.f;
#pragma unroll
        for (int k = 0; k < 64; k += 4) {
            float4 zv = *(const float4*)&zs[r * 64 + k];
            acc += zv.x * wsm[(k + 0) * 64 + lane];
            acc += zv.y * wsm[(k + 1) * 64 + lane];
            acc += zv.z * wsm[(k + 2) * 64 + lane];
            acc += zv.w * wsm[(k + 3) * 64 + lane];
        }
        acc += bv;
        int gr = r0 + r;
        if (gr < NN) {
            out[gr * HC + lane] = acc;
            ssum += acc;
            ssq += acc * acc;
        }
    }
    __shared__ float red[512];
    red[t] = ssum;
    red[256 + t] = ssq;
    __syncthreads();
    if (wid == 0) {
        float ts = red[lane] + red[64 + lane] + red[128 + lane] + red[192 + lane];
        float t2 = red[256 + lane] + red[256 + 64 + lane] + red[256 + 128 + lane] +
                   red[256 + 192 + lane];
        atomicAdd(&statsOut[lane], ts);
        atomicAdd(&statsOut[64 + lane], t2);
    }
}

// ---------------- BN2 + ReLU + h write + sorted segmented graph sum ----------------
#define CHK 32
__global__ void bn_relu_seg_kernel(const float* __restrict__ u, const float* __restrict__ stats,
                                   const float* __restrict__ g, const float* __restrict__ b,
                                   const int* __restrict__ batch, float* __restrict__ h,
                                   float* __restrict__ gdesc, int layer) {
    int lane = threadIdx.x & 63;
    int wid = threadIdx.x >> 6;
    int i0 = (blockIdx.x * 4 + wid) * CHK;
    if (i0 >= NN) return;
    float mu = stats[lane] * (1.0f / NN);
    float var = stats[64 + lane] * (1.0f / NN) - mu * mu;
    float a = g[lane] * rsqrtf(var + BN_EPS);
    float s = b[lane] - mu * a;
    int col = 1 + layer * HC + lane;
    float acc = 0.f;
    int cur = -1;
    int iend = i0 + CHK;
    if (iend > NN) iend = NN;
    for (int i = i0; i < iend; ++i) {
        int gid = batch[i];
        if (gid != cur) {
            if (cur >= 0) atomicAdd(&gdesc[cur * GD_COLS + col], acc);
            cur = gid;
            acc = 0.f;
        }
        float v = fmaxf(u[i * HC + lane] * a + s, 0.f);
        h[i * HC + lane] = v;
        acc += v;
    }
    if (cur >= 0) atomicAdd(&gdesc[cur * GD_COLS + col], acc);
}

__global__ void first_desc_kernel(const float* __restrict__ x, const int* __restrict__ batch,
                                  float* __restrict__ gdesc) {
    int i = blockIdx.x * blockDim.x + threadIdx.x;
    if (i < NN) atomicAdd(&gdesc[batch[i] * GD_COLS], x[i]);
}

__global__ void final_gemm_kernel(const float* __restrict__ gdesc, const float* __restrict__ lw,
                                  const float* __restrict__ lb, float* __restrict__ out) {
    int g = blockIdx.x;
    int lane = threadIdx.x;  // 64
    float a0 = 0.f, a1 = 0.f;
    for (int j = lane; j < GD_COLS; j += 64) {
        float v = gdesc[g * GD_COLS + j];
        a0 += v * lw[j * 2 + 0];
        a1 += v * lw[j * 2 + 1];
    }
    for (int off = 32; off > 0; off >>= 1) {
        a0 += __shfl_down(a0, off);
        a1 += __shfl_down(a1, off);
    }
    if (lane == 0) {
        out[g * 2 + 0] = a0 + lb[0];
        out[g * 2 + 1] = a1 + lb[1];
    }
}

extern "C" void kernel_launch(void* const* d_in, const int* in_sizes, int n_in, void* d_out,
                              int out_size, void* d_ws, size_t ws_size, hipStream_t stream) {
    const float* x = (const float*)d_in[0];
    const int* ei = (const int*)d_in[1];
    const int* batch = (const int*)d_in[2];
    const float* w1_0 = (const float*)d_in[3];
    const float* w1_rest = (const float*)d_in[4];
    const float* b1 = (const float*)d_in[5];
    const float* gm = (const float*)d_in[6];
    const float* bm = (const float*)d_in[7];
    const float* w2 = (const float*)d_in[8];
    const float* b2 = (const float*)d_in[9];
    const float* go = (const float*)d_in[10];
    const float* bo = (const float*)d_in[11];
    const float* lw = (const float*)d_in[12];
    const float* lb = (const float*)d_in[13];
    float* out = (float*)d_out;

    float* hbuf = (float*)d_ws;                 // N*64
    float* ybuf = hbuf + (size_t)NN * HC;       // N*64
    float* ubuf = ybuf + (size_t)NN * HC;       // N*64
    float* z0 = ubuf + (size_t)NN * HC;         // N
    float* stats = z0 + NN;                     // NL*256
    float* gdesc = stats + NL * 256;            // NG*321
    int* row_start = (int*)(gdesc + (size_t)NG * GD_COLS);  // NN+1
    int* cursor = row_start + NN + 1;           // NN (also counts)
    int* tile_sums = cursor + NN;               // 256
    int* ssrc = tile_sums + 256;                // NE

    hipMemsetAsync(stats, 0, (NL * 256 + NG * GD_COLS) * sizeof(float), stream);
    hipMemsetAsync(cursor, 0, NN * sizeof(int), stream);  // counts

    // ---- CSR build (once; edges constant across layers) ----
    hist_kernel<<<(NE + 255) / 256, 256, 0, stream>>>(ei, cursor);
    scan_a_kernel<<<NT, 256, 0, stream>>>(cursor, row_start, tile_sums);
    scan_b_kernel<<<1, 256, 0, stream>>>(tile_sums);
    scan_c_kernel<<<NT, 256, 0, stream>>>(row_start, tile_sums, cursor);
    scatter_kernel<<<(NE + 255) / 256, 256, 0, stream>>>(ei, cursor, ssrc);

    // ---- layer 0 ----
    gather0_kernel<<<NT, 256, 0, stream>>>(x, row_start, ssrc, z0);
    rank1_stats_kernel<<<(NN + 255) / 256, 256, 0, stream>>>(z0, w1_0, b1, ybuf, stats);
    gemm64_norm_kernel<<<(NN + 63) / 64, 256, 0, stream>>>(ybuf, w2, b2, stats, gm, bm, ubuf,
                                                           stats + 128);
    bn_relu_seg_kernel<<<(NN + 4 * CHK - 1) / (4 * CHK), 256, 0, stream>>>(
        ubuf, stats + 128, go, bo, batch, hbuf, gdesc, 0);

    // ---- layers 1..4 ----
    for (int l = 1; l < NL; ++l) {
        float* st1 = stats + l * 256;
        float* st2 = st1 + 128;
        gather_gemm_kernel<<<(NN + 63) / 64, 256, 0, stream>>>(
            hbuf, row_start, ssrc, w1_rest + (size_t)(l - 1) * HC * HC, b1 + l * HC, ybuf, st1);
        gemm64_norm_kernel<<<(NN + 63) / 64, 256, 0, stream>>>(
            ybuf, w2 + (size_t)l * HC * HC, b2 + l * HC, st1, gm + l * HC, bm + l * HC, ubuf, st2);
        bn_relu_seg_kernel<<<(NN + 4 * CHK - 1) / (4 * CHK), 256, 0, stream>>>(
            ubuf, st2, go + l * HC, bo + l * HC, batch, hbuf, gdesc, l);
    }

    first_desc_kernel<<<(NN + 255) / 256, 256, 0, stream>>>(x, batch, gdesc);
    final_gemm_kernel<<<NG, 64, 0, stream>>>(gdesc, lw, lb, out);
}

// Round 3
// 953.922 us; speedup vs baseline: 1.4903x; 1.2031x over previous
//
#include <hip/hip_runtime.h>

#define NN 50000
#define NE 800000
#define NG 512
#define HC 64
#define NL 5
#define GD_COLS 321
#define BN_EPS 1e-5f
#define NT 196  // scan tiles of 256 covering NN

// ---------------- CSR build (edges sorted by dst), done once per call ----------------

__global__ void hist_kernel(const int* __restrict__ ei, int* __restrict__ counts) {
    int e = blockIdx.x * blockDim.x + threadIdx.x;
    if (e < NE) atomicAdd(&counts[ei[NE + e]], 1);
}

__global__ void scan_a_kernel(const int* __restrict__ counts, int* __restrict__ row_start,
                              int* __restrict__ tile_sums) {
    __shared__ int sh[256];
    int t = threadIdx.x;
    int i = blockIdx.x * 256 + t;
    int c = (i < NN) ? counts[i] : 0;
    sh[t] = c;
    __syncthreads();
    for (int ofs = 1; ofs < 256; ofs <<= 1) {
        int v = (t >= ofs) ? sh[t - ofs] : 0;
        __syncthreads();
        sh[t] += v;
        __syncthreads();
    }
    if (i < NN) row_start[i] = sh[t] - c;
    if (t == 255) tile_sums[blockIdx.x] = sh[255];
}

__global__ void scan_b_kernel(int* __restrict__ tile_sums) {
    __shared__ int sh[256];
    int t = threadIdx.x;
    int v = (t < NT) ? tile_sums[t] : 0;
    sh[t] = v;
    __syncthreads();
    for (int ofs = 1; ofs < 256; ofs <<= 1) {
        int u = (t >= ofs) ? sh[t - ofs] : 0;
        __syncthreads();
        sh[t] += u;
        __syncthreads();
    }
    if (t < NT) tile_sums[t] = sh[t] - v;
}

__global__ void scan_c_kernel(int* __restrict__ row_start, const int* __restrict__ tile_sums,
                              int* __restrict__ cursor) {
    int i = blockIdx.x * 256 + threadIdx.x;
    if (i < NN) {
        int v = row_start[i] + tile_sums[blockIdx.x];
        row_start[i] = v;
        cursor[i] = v;
    }
    if (i == 0) row_start[NN] = NE;
}

__global__ void scatter_kernel(const int* __restrict__ ei, int* __restrict__ cursor,
                               int* __restrict__ ssrc) {
    int e = blockIdx.x * blockDim.x + threadIdx.x;
    if (e < NE) {
        int d = ei[NE + e];
        int pos = atomicAdd(&cursor[d], 1);
        ssrc[pos] = ei[e];
    }
}

// ---------------- layer 0 (C_IN = 1) ----------------

__global__ void gather0_kernel(const float* __restrict__ x, const int* __restrict__ row_start,
                               const int* __restrict__ ssrc, float* __restrict__ z0) {
    int i = blockIdx.x * blockDim.x + threadIdx.x;
    if (i < NN) {
        float acc = x[i];
        int p = row_start[i];
        int pb = row_start[i + 1];
        for (; p + 4 <= pb; p += 4) {
            int s0 = ssrc[p], s1 = ssrc[p + 1], s2 = ssrc[p + 2], s3 = ssrc[p + 3];
            float v0 = x[s0], v1 = x[s1], v2 = x[s2], v3 = x[s3];
            acc += (v0 + v1) + (v2 + v3);
        }
        for (; p < pb; ++p) acc += x[ssrc[p]];
        z0[i] = acc;
    }
}

// y[r][c] = z0[r]*w1_0[c] + b1[c]; accumulate per-channel sum/sumsq
__global__ void rank1_stats_kernel(const float* __restrict__ z0, const float* __restrict__ w,
                                   const float* __restrict__ bias, float* __restrict__ y,
                                   float* __restrict__ stats) {
    int lane = threadIdx.x & 63;
    int wid = threadIdx.x >> 6;
    int r0 = blockIdx.x * 64 + wid * 16;
    float wv = w[lane];
    float bv = bias[lane];
    float s = 0.f, s2 = 0.f;
    for (int j = 0; j < 16; ++j) {
        int r = r0 + j;
        if (r < NN) {
            float v = z0[r] * wv + bv;
            y[r * HC + lane] = v;
            s += v;
            s2 += v * v;
        }
    }
    __shared__ float ls[256], ls2[256];
    ls[threadIdx.x] = s;
    ls2[threadIdx.x] = s2;
    __syncthreads();
    if (wid == 0) {
        float ts = ls[lane] + ls[64 + lane] + ls[128 + lane] + ls[192 + lane];
        float t2 = ls2[lane] + ls2[64 + lane] + ls2[128 + lane] + ls2[192 + lane];
        atomicAdd(&stats[lane], ts);
        atomicAdd(&stats[64 + lane], t2);
    }
}

// ---------------- fused gather + GEMM1 + stats (layers 1..4) ----------------
// 32 nodes/block, 8 per wave. 8-way unrolled edge loop for MLP.
__global__ __launch_bounds__(256) void gather_gemm_kernel(
    const float* __restrict__ h, const int* __restrict__ row_start, const int* __restrict__ ssrc,
    const float* __restrict__ w, const float* __restrict__ bias, float* __restrict__ out,
    float* __restrict__ statsOut) {
    __shared__ float zs[32 * 64];
    __shared__ float wsm[64 * 64];
    __shared__ float red[512];
    int t = threadIdx.x, lane = t & 63, wid = t >> 6;
    int r0 = blockIdx.x * 32;
    for (int idx = t; idx < 1024; idx += 256)
        *(float4*)&wsm[idx * 4] = *(const float4*)&w[idx * 4];
    for (int j = 0; j < 8; ++j) {
        int lr = wid * 8 + j;
        int gr = r0 + lr;
        float acc = 0.f;
        if (gr < NN) {
            acc = h[gr * HC + lane];
            int p = row_start[gr];
            int pb = row_start[gr + 1];
            for (; p + 8 <= pb; p += 8) {
                int s0 = ssrc[p + 0], s1 = ssrc[p + 1], s2 = ssrc[p + 2], s3 = ssrc[p + 3];
                int s4 = ssrc[p + 4], s5 = ssrc[p + 5], s6 = ssrc[p + 6], s7 = ssrc[p + 7];
                float v0 = h[s0 * HC + lane], v1 = h[s1 * HC + lane];
                float v2 = h[s2 * HC + lane], v3 = h[s3 * HC + lane];
                float v4 = h[s4 * HC + lane], v5 = h[s5 * HC + lane];
                float v6 = h[s6 * HC + lane], v7 = h[s7 * HC + lane];
                acc += ((v0 + v1) + (v2 + v3)) + ((v4 + v5) + (v6 + v7));
            }
            for (; p < pb; ++p) acc += h[ssrc[p] * HC + lane];
        }
        zs[lr * 64 + lane] = acc;
    }
    __syncthreads();
    float bv = bias[lane];
    float ssum = 0.f, ssq = 0.f;
    for (int j = 0; j < 8; ++j) {
        int r = wid * 8 + j;
        float acc = 0.f;
#pragma unroll
        for (int k = 0; k < 64; k += 4) {
            float4 zv = *(const float4*)&zs[r * 64 + k];
            acc += zv.x * wsm[(k + 0) * 64 + lane];
            acc += zv.y * wsm[(k + 1) * 64 + lane];
            acc += zv.z * wsm[(k + 2) * 64 + lane];
            acc += zv.w * wsm[(k + 3) * 64 + lane];
        }
        acc += bv;
        int gr = r0 + r;
        if (gr < NN) {
            out[gr * HC + lane] = acc;
            ssum += acc;
            ssq += acc * acc;
        }
    }
    red[t] = ssum;
    __syncthreads();
    if (wid == 0) {
        float ts = red[lane] + red[64 + lane] + red[128 + lane] + red[192 + lane];
        atomicAdd(&statsOut[lane], ts);
    }
    __syncthreads();
    red[t] = ssq;
    __syncthreads();
    if (wid == 0) {
        float t2 = red[lane] + red[64 + lane] + red[128 + lane] + red[192 + lane];
        atomicAdd(&statsOut[64 + lane], t2);
    }
}

// ---------------- BN1+ReLU fused into GEMM2 + stats (32 rows/block) ----------------
__global__ __launch_bounds__(256) void gemm64_norm_kernel(
    const float* __restrict__ in, const float* __restrict__ w, const float* __restrict__ bias,
    const float* __restrict__ statsIn, const float* __restrict__ gIn,
    const float* __restrict__ bIn, float* __restrict__ out, float* __restrict__ statsOut) {
    __shared__ float zs[32 * 64];
    __shared__ float wsm[64 * 64];
    __shared__ float a1[64], s1[64];
    __shared__ float red[512];
    int t = threadIdx.x;
    if (t < 64) {
        float mu = statsIn[t] * (1.0f / NN);
        float var = statsIn[64 + t] * (1.0f / NN) - mu * mu;
        float a = gIn[t] * rsqrtf(var + BN_EPS);
        a1[t] = a;
        s1[t] = bIn[t] - mu * a;
    }
    __syncthreads();
    int r0 = blockIdx.x * 32;
    for (int idx = t; idx < 512; idx += 256) {
        int off = idx * 4;
        int r = r0 + (off >> 6);
        int k = off & 63;
        float4 v;
        if (r < NN)
            v = *(const float4*)&in[r * HC + k];
        else
            v = make_float4(0.f, 0.f, 0.f, 0.f);
        v.x = fmaxf(v.x * a1[k] + s1[k], 0.f);
        v.y = fmaxf(v.y * a1[k + 1] + s1[k + 1], 0.f);
        v.z = fmaxf(v.z * a1[k + 2] + s1[k + 2], 0.f);
        v.w = fmaxf(v.w * a1[k + 3] + s1[k + 3], 0.f);
        *(float4*)&zs[off] = v;
    }
    for (int idx = t; idx < 1024; idx += 256) {
        int off = idx * 4;
        *(float4*)&wsm[off] = *(const float4*)&w[off];
    }
    __syncthreads();
    int lane = t & 63, wid = t >> 6;
    float bv = bias[lane];
    float ssum = 0.f, ssq = 0.f;
    for (int j = 0; j < 8; ++j) {
        int r = wid * 8 + j;
        float acc = 0.f;
#pragma unroll
        for (int k = 0; k < 64; k += 4) {
            float4 zv = *(const float4*)&zs[r * 64 + k];
            acc += zv.x * wsm[(k + 0) * 64 + lane];
            acc += zv.y * wsm[(k + 1) * 64 + lane];
            acc += zv.z * wsm[(k + 2) * 64 + lane];
            acc += zv.w * wsm[(k + 3) * 64 + lane];
        }
        acc += bv;
        int gr = r0 + r;
        if (gr < NN) {
            out[gr * HC + lane] = acc;
            ssum += acc;
            ssq += acc * acc;
        }
    }
    red[t] = ssum;
    __syncthreads();
    if (wid == 0) {
        float ts = red[lane] + red[64 + lane] + red[128 + lane] + red[192 + lane];
        atomicAdd(&statsOut[lane], ts);
    }
    __syncthreads();
    red[t] = ssq;
    __syncthreads();
    if (wid == 0) {
        float t2 = red[lane] + red[64 + lane] + red[128 + lane] + red[192 + lane];
        atomicAdd(&statsOut[64 + lane], t2);
    }
}

// ---------------- BN2 + ReLU + h write + sorted segmented graph sum ----------------
#define CHK 16
__global__ void bn_relu_seg_kernel(const float* __restrict__ u, const float* __restrict__ stats,
                                   const float* __restrict__ g, const float* __restrict__ b,
                                   const int* __restrict__ batch, float* __restrict__ h,
                                   float* __restrict__ gdesc, int layer) {
    int lane = threadIdx.x & 63;
    int wid = threadIdx.x >> 6;
    int i0 = (blockIdx.x * 4 + wid) * CHK;
    if (i0 >= NN) return;
    float mu = stats[lane] * (1.0f / NN);
    float var = stats[64 + lane] * (1.0f / NN) - mu * mu;
    float a = g[lane] * rsqrtf(var + BN_EPS);
    float s = b[lane] - mu * a;
    int col = 1 + layer * HC + lane;
    float acc = 0.f;
    int cur = -1;
    int iend = i0 + CHK;
    if (iend > NN) iend = NN;
    for (int i = i0; i < iend; ++i) {
        int gid = batch[i];
        if (gid != cur) {
            if (cur >= 0) atomicAdd(&gdesc[cur * GD_COLS + col], acc);
            cur = gid;
            acc = 0.f;
        }
        float v = fmaxf(u[i * HC + lane] * a + s, 0.f);
        h[i * HC + lane] = v;
        acc += v;
    }
    if (cur >= 0) atomicAdd(&gdesc[cur * GD_COLS + col], acc);
}

__global__ void first_desc_kernel(const float* __restrict__ x, const int* __restrict__ batch,
                                  float* __restrict__ gdesc) {
    int i = blockIdx.x * blockDim.x + threadIdx.x;
    if (i < NN) atomicAdd(&gdesc[batch[i] * GD_COLS], x[i]);
}

__global__ void final_gemm_kernel(const float* __restrict__ gdesc, const float* __restrict__ lw,
                                  const float* __restrict__ lb, float* __restrict__ out) {
    int g = blockIdx.x;
    int lane = threadIdx.x;  // 64
    float a0 = 0.f, a1 = 0.f;
    for (int j = lane; j < GD_COLS; j += 64) {
        float v = gdesc[g * GD_COLS + j];
        a0 += v * lw[j * 2 + 0];
        a1 += v * lw[j * 2 + 1];
    }
    for (int off = 32; off > 0; off >>= 1) {
        a0 += __shfl_down(a0, off);
        a1 += __shfl_down(a1, off);
    }
    if (lane == 0) {
        out[g * 2 + 0] = a0 + lb[0];
        out[g * 2 + 1] = a1 + lb[1];
    }
}

extern "C" void kernel_launch(void* const* d_in, const int* in_sizes, int n_in, void* d_out,
                              int out_size, void* d_ws, size_t ws_size, hipStream_t stream) {
    const float* x = (const float*)d_in[0];
    const int* ei = (const int*)d_in[1];
    const int* batch = (const int*)d_in[2];
    const float* w1_0 = (const float*)d_in[3];
    const float* w1_rest = (const float*)d_in[4];
    const float* b1 = (const float*)d_in[5];
    const float* gm = (const float*)d_in[6];
    const float* bm = (const float*)d_in[7];
    const float* w2 = (const float*)d_in[8];
    const float* b2 = (const float*)d_in[9];
    const float* go = (const float*)d_in[10];
    const float* bo = (const float*)d_in[11];
    const float* lw = (const float*)d_in[12];
    const float* lb = (const float*)d_in[13];
    float* out = (float*)d_out;

    float* hbuf = (float*)d_ws;                 // N*64
    float* ybuf = hbuf + (size_t)NN * HC;       // N*64
    float* ubuf = ybuf + (size_t)NN * HC;       // N*64
    float* z0 = ubuf + (size_t)NN * HC;         // N
    float* stats = z0 + NN;                     // NL*256
    float* gdesc = stats + NL * 256;            // NG*321
    int* row_start = (int*)(gdesc + (size_t)NG * GD_COLS);  // NN+1
    int* cursor = row_start + NN + 1;           // NN (also counts)
    int* tile_sums = cursor + NN;               // 256
    int* ssrc = tile_sums + 256;                // NE

    hipMemsetAsync(stats, 0, (NL * 256 + NG * GD_COLS) * sizeof(float), stream);
    hipMemsetAsync(cursor, 0, NN * sizeof(int), stream);  // counts

    // ---- CSR build (once; edges constant across layers) ----
    hist_kernel<<<(NE + 255) / 256, 256, 0, stream>>>(ei, cursor);
    scan_a_kernel<<<NT, 256, 0, stream>>>(cursor, row_start, tile_sums);
    scan_b_kernel<<<1, 256, 0, stream>>>(tile_sums);
    scan_c_kernel<<<NT, 256, 0, stream>>>(row_start, tile_sums, cursor);
    scatter_kernel<<<(NE + 255) / 256, 256, 0, stream>>>(ei, cursor, ssrc);

    // ---- layer 0 ----
    gather0_kernel<<<NT, 256, 0, stream>>>(x, row_start, ssrc, z0);
    rank1_stats_kernel<<<(NN + 63) / 64, 256, 0, stream>>>(z0, w1_0, b1, ybuf, stats);
    gemm64_norm_kernel<<<(NN + 31) / 32, 256, 0, stream>>>(ybuf, w2, b2, stats, gm, bm, ubuf,
                                                           stats + 128);
    bn_relu_seg_kernel<<<(NN + 4 * CHK - 1) / (4 * CHK), 256, 0, stream>>>(
        ubuf, stats + 128, go, bo, batch, hbuf, gdesc, 0);

    // ---- layers 1..4 ----
    for (int l = 1; l < NL; ++l) {
        float* st1 = stats + l * 256;
        float* st2 = st1 + 128;
        gather_gemm_kernel<<<(NN + 31) / 32, 256, 0, stream>>>(
            hbuf, row_start, ssrc, w1_rest + (size_t)(l - 1) * HC * HC, b1 + l * HC, ybuf, st1);
        gemm64_norm_kernel<<<(NN + 31) / 32, 256, 0, stream>>>(
            ybuf, w2 + (size_t)l * HC * HC, b2 + l * HC, st1, gm + l * HC, bm + l * HC, ubuf, st2);
        bn_relu_seg_kernel<<<(NN + 4 * CHK - 1) / (4 * CHK), 256, 0, stream>>>(
            ubuf, st2, go + l * HC, bo + l * HC, batch, hbuf, gdesc, l);
    }

    first_desc_kernel<<<(NN + 255) / 256, 256, 0, stream>>>(x, batch, gdesc);
    final_gemm_kernel<<<NG, 64, 0, stream>>>(gdesc, lw, lb, out);
}